// Round 15
// baseline (255.919 us; speedup 1.0000x reference)
//
#include <hip/hip_runtime.h>
#include <math.h>

typedef int intx4 __attribute__((ext_vector_type(4)));
typedef int intx8 __attribute__((ext_vector_type(8)));
typedef float floatx16 __attribute__((ext_vector_type(16)));

#define N_ROWS 8192
#define KDIM 1024

// E8M0 scale bytes: 123 -> 2^-4 per side (data pre-scaled by 2^4 each side)
#define SCALE_WORD 0x7B7B7B7B

// order-preserving float->int encoding for atomicMax
__device__ __forceinline__ int fenc(float f) {
  int i = __float_as_int(f);
  return i >= 0 ? i : (i ^ 0x7fffffff);
}
__device__ __forceinline__ float fdec(int e) {
  int b = e >= 0 ? e : (e ^ 0x7fffffff);
  return __int_as_float(b);
}

// async 16B global->LDS DMA (m97 pattern: per-lane global src, LDS dest must
// equal wave-uniform base + lane*16 -- ours does by construction).
__device__ __forceinline__ void gld_lds16(const void* g, void* l) {
  __builtin_amdgcn_global_load_lds(
      (const __attribute__((address_space(1))) unsigned int*)g,
      (__attribute__((address_space(3))) unsigned int*)l, 16, 0, 0);
}

// One WAVE per row (4 rows/block, no __syncthreads): computes 1/||x|| (fp32),
// writes row normalized*16 as e4m3 via HW cvt, inits the max slot.
__global__ __launch_bounds__(256) void normalize_kernel(
    const float* __restrict__ ex, const float* __restrict__ ey,
    unsigned char* __restrict__ exn, unsigned char* __restrict__ eyn,
    int* __restrict__ rowmax, int* __restrict__ colmax) {
  const int wave = threadIdx.x >> 6, lane = threadIdx.x & 63;
  const int gr = blockIdx.x * 4 + wave;  // 0..16383
  const float* x;
  unsigned char* out;
  int* mslot;
  int row;
  if (gr < N_ROWS) {
    x = ex; out = exn; mslot = rowmax; row = gr;
  } else {
    x = ey; out = eyn; mslot = colmax; row = gr - N_ROWS;
  }
  const float4* xr = (const float4*)(x + (size_t)row * KDIM);
  float4 v[4];
  float ss = 0.f;
#pragma unroll
  for (int j = 0; j < 4; ++j) {
    v[j] = xr[lane + j * 64];  // coalesced
    ss += v[j].x * v[j].x + v[j].y * v[j].y + v[j].z * v[j].z + v[j].w * v[j].w;
  }
#pragma unroll
  for (int off = 32; off > 0; off >>= 1) ss += __shfl_xor(ss, off, 64);
  const float rs = 16.0f * rsqrtf(fmaxf(ss, 1e-24f));  // 2^4 pre-scale
  int* op = (int*)(out + (size_t)row * KDIM);
#pragma unroll
  for (int j = 0; j < 4; ++j) {
    int w = __builtin_amdgcn_cvt_pk_fp8_f32(v[j].x * rs, v[j].y * rs, 0, false);
    w = __builtin_amdgcn_cvt_pk_fp8_f32(v[j].z * rs, v[j].w * rs, w, true);
    op[lane + j * 64] = w;
  }
  if (lane == 0) mslot[row] = (int)0x80000000;  // encoded -inf floor
}

// 256x256 tile GEMM (A @ B^T, row-major K-contiguous e4m3) using MX-scaled
// mfma_scale_f32_32x32x64_f8f6f4, fused with row/col max reduction.
//
// Round-26 = Round-25 resubmitted (r25 bench died to a container/infra
// failure, same signature as round 2 which passed on identical resubmit;
// design audit found no fault vector: DMA pattern verified m97 shape, all
// global/LDS addresses in-bounds, wave-uniform barriers, no dangling vmem).
//
// Round-25 change: clean re-test of barrier-halving (r24's theory) with
// the spill trigger removed. r24 post-mortem: WRITE 262 MB = exactly one
// 16-B frag8/thread/tile to scratch. Triggers vs clean r22: (a) union-half
// RD8 forces both b128 loads into one pre-allocated 8-tuple (harder
// constraint than lo/hi + shufflevector, which resolves to adjacent quads
// with no movs); (b) four hoisted (4g+c)*BK offsets live. At 16-wave
// budget (64 arch after 64 acc) that tipped it. Correction to the ledger:
// at 128 regs/thread occupancy is register-limited to 16 waves/CU = ONE
// 16-wave block even at 64 KB LDS, so 128 KB LDS is NOT a confound -- the
// r24 regression was purely spill.
// This round: EXACT r22 COMPUTE (shufflevector form, proven 64-arch
// clean) + 4-buffer LDS + {stage 2 tiles -> compute 2 tiles -> sync}
// with ROLLING global pointers and literal offsets (compiler folds into
// the instruction offset field; <= 2 extra live regs vs r22).
// Barrier count 15 -> 8; each stage gets >= 2 compute phases before the
// sync that drains it (better margin than r22).
// Race audit: buf staged at tile t was last read at tile t-2, before the
// previous __syncthreads (all waves passed it) -> no overwrite race; each
// sync's vmcnt(0) drain covers exactly the 2-tile group consumed next.
// Tripwires: WRITE ~20 MB / VGPR 64-arch (else this structure inherently
// over-pressures -> revert to r22); clean-but-110 => convoy is intrinsic
// lockstep burst, not barrier count -> r22 is the coarse-schedule plateau.
//
// LDS swizzle (verified r8): 64-B rows, 16-B chunk c of row r at slot
// c ^ ((r>>1)&3); staging pre-swizzles the per-lane global source chunk so
// the linear lane*16 dest lands swizzle-stored; fragment reads recover
// true chunk 2h+j -> operand bytes at (half,j,b) equal global
// k = k0+(2h+j)*16+b for BOTH A and B -> exact dot-product pairing.
// (Dest row = tid>>2 covers 0..255 at 1024 thr; f(row) = (tid>>3)&3;
// all read-row bases are multiples of 32 -> fsw invariant.)
__global__ __launch_bounds__(1024, 1) void gemm_max_kernel(
    const unsigned char* __restrict__ A, const unsigned char* __restrict__ B,
    int* __restrict__ rowmax, int* __restrict__ colmax) {
  constexpr int TM = 256, BK = 64, K = KDIM;
  constexpr int BUF = TM * BK;                          // 16 KB per buffer
  __shared__ __align__(16) unsigned char sA[4 * BUF];   // 64 KB
  __shared__ __align__(16) unsigned char sB[4 * BUF];   // 64 KB

  const int bm = blockIdx.x, bn = blockIdx.y;
  const int tid = threadIdx.x;  // 0..1023
  const int lane = tid & 63, wave = tid >> 6;
  const int wm = wave >> 2, wn = wave & 3;  // 4x4 waves of 64x64
  const int l32 = lane & 31, half = lane >> 5;
  const int fsw = (l32 >> 1) & 3;                 // f(row) = (row>>1)&3
  const int oLo = (((2 * half + 0) ^ fsw) << 4);  // swizzled slot offsets
  const int oHi = (((2 * half + 1) ^ fsw) << 4);

  const char* Ab = (const char*)(A + (size_t)bm * TM * K);
  const char* Bb = (const char*)(B + (size_t)bn * TM * K);

  floatx16 acc[2][2] = {};

  // Staging: 1024 lanes stage a 256x64 tile (16 KB) per array in ONE DMA.
  // Dest tid*16 -> row tid>>2 (0..255), slot tid&3.
  // Source chunk = (tid&3) ^ f(row) = (tid&3) ^ ((tid>>3)&3).
  const int src_c16 = (((tid & 3) ^ ((tid >> 3) & 3)) << 4);
  const char* gAr = Ab + (size_t)(tid >> 2) * K + src_c16;  // rolling
  const char* gBr = Bb + (size_t)(tid >> 2) * K + src_c16;  // rolling
  unsigned char* wA = sA + tid * 16;  // linear per-lane dest
  unsigned char* wB = sB + tid * 16;

  // koff is a compile-time literal offset from the rolling pointers; the
  // compiler folds it into the global_load_lds offset field (no live regs).
#define STAGE(koff, buf)                              \
  do {                                                \
    gld_lds16(gAr + (koff), wA + (buf)*BUF);          \
    gld_lds16(gBr + (koff), wB + (buf)*BUF);          \
  } while (0)

  // EXACT r22 COMPUTE (shufflevector fragment assembly; proven 64-arch).
#define COMPUTE(cur)                                                        \
  do {                                                                      \
    intx8 aF[2];                                                            \
    _Pragma("unroll") for (int mi = 0; mi < 2; ++mi) {                      \
      const unsigned char* aBase =                                          \
          &sA[(cur)*BUF + (wm * 64 + mi * 32 + l32) * BK];                  \
      const intx4 lo = *(const intx4*)(aBase + oLo);                        \
      const intx4 hi = *(const intx4*)(aBase + oHi);                        \
      aF[mi] = __builtin_shufflevector(lo, hi, 0, 1, 2, 3, 4, 5, 6, 7);     \
    }                                                                       \
    _Pragma("unroll") for (int ni = 0; ni < 2; ++ni) {                      \
      const unsigned char* bBase =                                          \
          &sB[(cur)*BUF + (wn * 64 + ni * 32 + l32) * BK];                  \
      const intx4 lo = *(const intx4*)(bBase + oLo);                        \
      const intx4 hi = *(const intx4*)(bBase + oHi);                        \
      const intx8 bF =                                                      \
          __builtin_shufflevector(lo, hi, 0, 1, 2, 3, 4, 5, 6, 7);          \
      _Pragma("unroll") for (int mi = 0; mi < 2; ++mi)                      \
          acc[mi][ni] = __builtin_amdgcn_mfma_scale_f32_32x32x64_f8f6f4(    \
              aF[mi], bF, acc[mi][ni], 0, 0, 0, SCALE_WORD, 0,              \
              SCALE_WORD);                                                  \
    }                                                                       \
  } while (0)

  // Prologue: tiles 0,1 -> bufs 0,1; drain -> resident.
  STAGE(0 * BK, 0);
  STAGE(1 * BK, 1);
  __syncthreads();

  // Steady state: {stage 2 tiles -> compute 2 tiles -> sync}; buffers
  // rotate mod 4; rolling pointers advance 4 tiles per iteration so all
  // stage offsets are literals (2..5 * BK).
#pragma unroll 1
  for (int g = 0; g < 3; ++g) {  // iteration g covers tiles 4g .. 4g+3
    STAGE(2 * BK, 2);            // tile 4g+2
    STAGE(3 * BK, 3);            // tile 4g+3
    COMPUTE(0);                  // tile 4g
    COMPUTE(1);                  // tile 4g+1
    __syncthreads();             // drains tiles 4g+2,4g+3
    STAGE(4 * BK, 0);            // tile 4g+4
    STAGE(5 * BK, 1);            // tile 4g+5
    COMPUTE(2);                  // tile 4g+2
    COMPUTE(3);                  // tile 4g+3
    __syncthreads();             // drains tiles 4g+4,4g+5
    gAr += 4 * BK;
    gBr += 4 * BK;
  }
  // Tail: tiles 12,13 resident in bufs 0,1 (gAr at 12*BK).
  STAGE(2 * BK, 2);  // tile 14
  STAGE(3 * BK, 3);  // tile 15
  COMPUTE(0);        // tile 12
  COMPUTE(1);        // tile 13
  __syncthreads();   // drains tiles 14,15
  COMPUTE(2);        // tile 14
  COMPUTE(3);        // tile 15

#undef STAGE
#undef COMPUTE

  // 32x32 C/D layout (m74/m101, dtype-independent):
  //   col = lane&31, row = (reg&3) + 8*(reg>>2) + 4*(lane>>5), reg in [0,16)
  // Row maxes: in-lane over ni, shuffle across 32 cols (masks 1..16 stay
  // within a half), l32==0 lanes write.
#pragma unroll
  for (int mi = 0; mi < 2; ++mi) {
#pragma unroll
    for (int reg = 0; reg < 16; ++reg) {
      float v = fmaxf(acc[mi][0][reg], acc[mi][1][reg]);
#pragma unroll
      for (int m = 1; m < 32; m <<= 1) v = fmaxf(v, __shfl_xor(v, m, 64));
      if (l32 == 0) {
        const int grow = bm * TM + wm * 64 + mi * 32 +
                         (reg & 3) + 8 * (reg >> 2) + 4 * half;
        atomicMax(&rowmax[grow], fenc(v));
      }
    }
  }
  // Col maxes: in-lane over mi,reg (32 vals), combine halves via xor 32.
#pragma unroll
  for (int ni = 0; ni < 2; ++ni) {
    float v = -3.402823466e38f;
#pragma unroll
    for (int mi = 0; mi < 2; ++mi)
#pragma unroll
      for (int reg = 0; reg < 16; ++reg) v = fmaxf(v, acc[mi][ni][reg]);
    v = fmaxf(v, __shfl_xor(v, 32, 64));
    if (half == 0) {
      const int gcol = bn * TM + wn * 64 + ni * 32 + l32;
      atomicMax(&colmax[gcol], fenc(v));
    }
  }
}

__global__ __launch_bounds__(1024) void finalize_kernel(
    const int* __restrict__ rowmax, const int* __restrict__ colmax,
    float* __restrict__ out) {
  const int tid = threadIdx.x;
  float s1 = 0.f, s2 = 0.f;
  for (int i = tid; i < N_ROWS; i += 1024) {
    s1 += 1.0f - fdec(rowmax[i]);
    s2 += 1.0f - fdec(colmax[i]);
  }
#pragma unroll
  for (int off = 32; off > 0; off >>= 1) {
    s1 += __shfl_down(s1, off, 64);
    s2 += __shfl_down(s2, off, 64);
  }
  __shared__ float r1[16], r2[16];
  if ((tid & 63) == 0) {
    r1[tid >> 6] = s1;
    r2[tid >> 6] = s2;
  }
  __syncthreads();
  if (tid == 0) {
    const double SIGMA = 0.3;
    const double H_CONST = 0.5 * log(2.0 * 3.14159265358979323846 * SIGMA * SIGMA) + 0.5;
    const float HS = (float)(H_CONST / SIGMA);
    float a1 = 0.f, a2 = 0.f;
#pragma unroll
    for (int w = 0; w < 16; ++w) {
      a1 += r1[w];
      a2 += r2[w];
    }
    out[0] = HS * a1;
    out[1] = HS * a2;
  }
}

extern "C" void kernel_launch(void* const* d_in, const int* in_sizes, int n_in,
                              void* d_out, int out_size, void* d_ws, size_t ws_size,
                              hipStream_t stream) {
  const float* ex = (const float*)d_in[0];
  const float* ey = (const float*)d_in[1];
  float* out = (float*)d_out;
  char* ws = (char*)d_ws;

  unsigned char* exn = (unsigned char*)ws;                                   // 8 MB
  unsigned char* eyn = (unsigned char*)(ws + (size_t)N_ROWS * KDIM);         // 8 MB
  int* rowmax = (int*)(ws + (size_t)N_ROWS * KDIM * 2);                      // 32 KB
  int* colmax = rowmax + N_ROWS;                                             // 32 KB

  normalize_kernel<<<2 * N_ROWS / 4, 256, 0, stream>>>(ex, ey, exn, eyn, rowmax, colmax);
  gemm_max_kernel<<<dim3(32, 32), 1024, 0, stream>>>(exn, eyn, rowmax, colmax);
  finalize_kernel<<<1, 1024, 0, stream>>>(rowmax, colmax, out);
}

// Round 16
// 250.086 us; speedup vs baseline: 1.0233x; 1.0233x over previous
//
#include <hip/hip_runtime.h>
#include <math.h>

typedef int intx4 __attribute__((ext_vector_type(4)));
typedef int intx8 __attribute__((ext_vector_type(8)));
typedef float floatx16 __attribute__((ext_vector_type(16)));

#define N_ROWS 8192
#define KDIM 1024

// E8M0 scale bytes: 123 -> 2^-4 per side (data pre-scaled by 2^4 each side)
#define SCALE_WORD 0x7B7B7B7B

// order-preserving float->int encoding for atomicMax
__device__ __forceinline__ int fenc(float f) {
  int i = __float_as_int(f);
  return i >= 0 ? i : (i ^ 0x7fffffff);
}
__device__ __forceinline__ float fdec(int e) {
  int b = e >= 0 ? e : (e ^ 0x7fffffff);
  return __int_as_float(b);
}

// async 16B global->LDS DMA (m97 pattern: per-lane global src, LDS dest must
// equal wave-uniform base + lane*16 -- ours does by construction).
__device__ __forceinline__ void gld_lds16(const void* g, void* l) {
  __builtin_amdgcn_global_load_lds(
      (const __attribute__((address_space(1))) unsigned int*)g,
      (__attribute__((address_space(3))) unsigned int*)l, 16, 0, 0);
}

// One WAVE per row (4 rows/block, no __syncthreads): computes 1/||x|| (fp32),
// writes row normalized*16 as e4m3 via HW cvt, inits the max slot.
__global__ __launch_bounds__(256) void normalize_kernel(
    const float* __restrict__ ex, const float* __restrict__ ey,
    unsigned char* __restrict__ exn, unsigned char* __restrict__ eyn,
    int* __restrict__ rowmax, int* __restrict__ colmax) {
  const int wave = threadIdx.x >> 6, lane = threadIdx.x & 63;
  const int gr = blockIdx.x * 4 + wave;  // 0..16383
  const float* x;
  unsigned char* out;
  int* mslot;
  int row;
  if (gr < N_ROWS) {
    x = ex; out = exn; mslot = rowmax; row = gr;
  } else {
    x = ey; out = eyn; mslot = colmax; row = gr - N_ROWS;
  }
  const float4* xr = (const float4*)(x + (size_t)row * KDIM);
  float4 v[4];
  float ss = 0.f;
#pragma unroll
  for (int j = 0; j < 4; ++j) {
    v[j] = xr[lane + j * 64];  // coalesced
    ss += v[j].x * v[j].x + v[j].y * v[j].y + v[j].z * v[j].z + v[j].w * v[j].w;
  }
#pragma unroll
  for (int off = 32; off > 0; off >>= 1) ss += __shfl_xor(ss, off, 64);
  const float rs = 16.0f * rsqrtf(fmaxf(ss, 1e-24f));  // 2^4 pre-scale
  int* op = (int*)(out + (size_t)row * KDIM);
#pragma unroll
  for (int j = 0; j < 4; ++j) {
    int w = __builtin_amdgcn_cvt_pk_fp8_f32(v[j].x * rs, v[j].y * rs, 0, false);
    w = __builtin_amdgcn_cvt_pk_fp8_f32(v[j].z * rs, v[j].w * rs, w, true);
    op[lane + j * 64] = w;
  }
  if (lane == 0) mslot[row] = (int)0x80000000;  // encoded -inf floor
}

// 256x256 tile GEMM (A @ B^T, row-major K-contiguous e4m3) using MX-scaled
// mfma_scale_f32_32x32x64_f8f6f4, fused with row/col max reduction.
//
// Round-27 change: r26 + sched_barrier(0) between the two COMPUTEs of
// each group. Spill forensics across r24/r26: IDENTICAL 262 MB WRITE
// (16 B/thread/tile) with BOTH union-RD8 and shufflevector COMPUTE =>
// the trigger is back-to-back COMPUTE;COMPUTE with no fence. In r22 the
// per-tile __syncthreads doubled as a compiler scheduling fence; without
// it the scheduler software-pipelines across tiles (hoists tile-1's
// ds_reads above tile-0's MFMAs), peak live fragments exceed the 64-arch
// budget, and exactly one 16-B fragment/tile spills. Fix: a pure
// compile-time motion fence -- __builtin_amdgcn_sched_barrier(0) -- at
// the tile boundary inside each group. Zero runtime cost; restores r22's
// proven per-tile codegen while keeping runtime barriers HALVED (8 vs
// 15). Bonus vs r22: the youngest stage now has ~2 compute phases before
// the sync that drains it.
// Race audit (unchanged from r26): buf staged at tile t was last read at
// tile t-2, before the previous __syncthreads -> no overwrite race; each
// sync's vmcnt(0) drain covers exactly the 2-tile group consumed next.
// Tripwires: WRITE ~20 MB / VGPR 64-arch clean. If STILL spills -> the
// 4-buffer structure inherently over-pressures at this budget -> revert
// to r22 (coarse-schedule plateau). If clean-but-110 -> convoy is not
// barrier-count-bound; r22 is the plateau.
//
// LDS swizzle (verified r8): 64-B rows, 16-B chunk c of row r at slot
// c ^ ((r>>1)&3); staging pre-swizzles the per-lane global source chunk so
// the linear lane*16 dest lands swizzle-stored; fragment reads recover
// true chunk 2h+j -> operand bytes at (half,j,b) equal global
// k = k0+(2h+j)*16+b for BOTH A and B -> exact dot-product pairing.
// (Dest row = tid>>2 covers 0..255 at 1024 thr; f(row) = (tid>>3)&3;
// all read-row bases are multiples of 32 -> fsw invariant.)
__global__ __launch_bounds__(1024, 1) void gemm_max_kernel(
    const unsigned char* __restrict__ A, const unsigned char* __restrict__ B,
    int* __restrict__ rowmax, int* __restrict__ colmax) {
  constexpr int TM = 256, BK = 64, K = KDIM;
  constexpr int BUF = TM * BK;                          // 16 KB per buffer
  __shared__ __align__(16) unsigned char sA[4 * BUF];   // 64 KB
  __shared__ __align__(16) unsigned char sB[4 * BUF];   // 64 KB

  const int bm = blockIdx.x, bn = blockIdx.y;
  const int tid = threadIdx.x;  // 0..1023
  const int lane = tid & 63, wave = tid >> 6;
  const int wm = wave >> 2, wn = wave & 3;  // 4x4 waves of 64x64
  const int l32 = lane & 31, half = lane >> 5;
  const int fsw = (l32 >> 1) & 3;                 // f(row) = (row>>1)&3
  const int oLo = (((2 * half + 0) ^ fsw) << 4);  // swizzled slot offsets
  const int oHi = (((2 * half + 1) ^ fsw) << 4);

  const char* Ab = (const char*)(A + (size_t)bm * TM * K);
  const char* Bb = (const char*)(B + (size_t)bn * TM * K);

  floatx16 acc[2][2] = {};

  // Staging: 1024 lanes stage a 256x64 tile (16 KB) per array in ONE DMA.
  // Dest tid*16 -> row tid>>2 (0..255), slot tid&3.
  // Source chunk = (tid&3) ^ f(row) = (tid&3) ^ ((tid>>3)&3).
  const int src_c16 = (((tid & 3) ^ ((tid >> 3) & 3)) << 4);
  const char* gAr = Ab + (size_t)(tid >> 2) * K + src_c16;  // rolling
  const char* gBr = Bb + (size_t)(tid >> 2) * K + src_c16;  // rolling
  unsigned char* wA = sA + tid * 16;  // linear per-lane dest
  unsigned char* wB = sB + tid * 16;

  // koff is a compile-time literal offset from the rolling pointers; the
  // compiler folds it into the global_load_lds offset field (no live regs).
#define STAGE(koff, buf)                              \
  do {                                                \
    gld_lds16(gAr + (koff), wA + (buf)*BUF);          \
    gld_lds16(gBr + (koff), wB + (buf)*BUF);          \
  } while (0)

  // compile-time motion fence: prevents cross-tile hoisting of ds_reads
  // (the r24/r26 spill trigger). Zero runtime instructions.
#define FENCE() __builtin_amdgcn_sched_barrier(0)

  // EXACT r22 COMPUTE (shufflevector fragment assembly; proven 64-arch).
#define COMPUTE(cur)                                                        \
  do {                                                                      \
    intx8 aF[2];                                                            \
    _Pragma("unroll") for (int mi = 0; mi < 2; ++mi) {                      \
      const unsigned char* aBase =                                          \
          &sA[(cur)*BUF + (wm * 64 + mi * 32 + l32) * BK];                  \
      const intx4 lo = *(const intx4*)(aBase + oLo);                        \
      const intx4 hi = *(const intx4*)(aBase + oHi);                        \
      aF[mi] = __builtin_shufflevector(lo, hi, 0, 1, 2, 3, 4, 5, 6, 7);     \
    }                                                                       \
    _Pragma("unroll") for (int ni = 0; ni < 2; ++ni) {                      \
      const unsigned char* bBase =                                          \
          &sB[(cur)*BUF + (wn * 64 + ni * 32 + l32) * BK];                  \
      const intx4 lo = *(const intx4*)(bBase + oLo);                        \
      const intx4 hi = *(const intx4*)(bBase + oHi);                        \
      const intx8 bF =                                                      \
          __builtin_shufflevector(lo, hi, 0, 1, 2, 3, 4, 5, 6, 7);          \
      _Pragma("unroll") for (int mi = 0; mi < 2; ++mi)                      \
          acc[mi][ni] = __builtin_amdgcn_mfma_scale_f32_32x32x64_f8f6f4(    \
              aF[mi], bF, acc[mi][ni], 0, 0, 0, SCALE_WORD, 0,              \
              SCALE_WORD);                                                  \
    }                                                                       \
  } while (0)

  // Prologue: tiles 0,1 -> bufs 0,1; drain -> resident.
  STAGE(0 * BK, 0);
  STAGE(1 * BK, 1);
  __syncthreads();

  // Steady state: {stage 2 tiles -> compute 2 tiles -> sync}; buffers
  // rotate mod 4; rolling pointers advance 4 tiles per iteration so all
  // stage offsets are literals (2..5 * BK). FENCE() at each tile
  // boundary pins per-tile codegen (no cross-tile fragment hoisting).
#pragma unroll 1
  for (int g = 0; g < 3; ++g) {  // iteration g covers tiles 4g .. 4g+3
    STAGE(2 * BK, 2);            // tile 4g+2
    STAGE(3 * BK, 3);            // tile 4g+3
    FENCE();
    COMPUTE(0);                  // tile 4g
    FENCE();
    COMPUTE(1);                  // tile 4g+1
    __syncthreads();             // drains tiles 4g+2,4g+3
    STAGE(4 * BK, 0);            // tile 4g+4
    STAGE(5 * BK, 1);            // tile 4g+5
    FENCE();
    COMPUTE(2);                  // tile 4g+2
    FENCE();
    COMPUTE(3);                  // tile 4g+3
    __syncthreads();             // drains tiles 4g+4,4g+5
    gAr += 4 * BK;
    gBr += 4 * BK;
  }
  // Tail: tiles 12,13 resident in bufs 0,1 (gAr at 12*BK).
  STAGE(2 * BK, 2);  // tile 14
  STAGE(3 * BK, 3);  // tile 15
  FENCE();
  COMPUTE(0);        // tile 12
  FENCE();
  COMPUTE(1);        // tile 13
  __syncthreads();   // drains tiles 14,15
  COMPUTE(2);        // tile 14
  FENCE();
  COMPUTE(3);        // tile 15

#undef STAGE
#undef FENCE
#undef COMPUTE

  // 32x32 C/D layout (m74/m101, dtype-independent):
  //   col = lane&31, row = (reg&3) + 8*(reg>>2) + 4*(lane>>5), reg in [0,16)
  // Row maxes: in-lane over ni, shuffle across 32 cols (masks 1..16 stay
  // within a half), l32==0 lanes write.
#pragma unroll
  for (int mi = 0; mi < 2; ++mi) {
#pragma unroll
    for (int reg = 0; reg < 16; ++reg) {
      float v = fmaxf(acc[mi][0][reg], acc[mi][1][reg]);
#pragma unroll
      for (int m = 1; m < 32; m <<= 1) v = fmaxf(v, __shfl_xor(v, m, 64));
      if (l32 == 0) {
        const int grow = bm * TM + wm * 64 + mi * 32 +
                         (reg & 3) + 8 * (reg >> 2) + 4 * half;
        atomicMax(&rowmax[grow], fenc(v));
      }
    }
  }
  // Col maxes: in-lane over mi,reg (32 vals), combine halves via xor 32.
#pragma unroll
  for (int ni = 0; ni < 2; ++ni) {
    float v = -3.402823466e38f;
#pragma unroll
    for (int mi = 0; mi < 2; ++mi)
#pragma unroll
      for (int reg = 0; reg < 16; ++reg) v = fmaxf(v, acc[mi][ni][reg]);
    v = fmaxf(v, __shfl_xor(v, 32, 64));
    if (half == 0) {
      const int gcol = bn * TM + wn * 64 + ni * 32 + l32;
      atomicMax(&colmax[gcol], fenc(v));
    }
  }
}

__global__ __launch_bounds__(1024) void finalize_kernel(
    const int* __restrict__ rowmax, const int* __restrict__ colmax,
    float* __restrict__ out) {
  const int tid = threadIdx.x;
  float s1 = 0.f, s2 = 0.f;
  for (int i = tid; i < N_ROWS; i += 1024) {
    s1 += 1.0f - fdec(rowmax[i]);
    s2 += 1.0f - fdec(colmax[i]);
  }
#pragma unroll
  for (int off = 32; off > 0; off >>= 1) {
    s1 += __shfl_down(s1, off, 64);
    s2 += __shfl_down(s2, off, 64);
  }
  __shared__ float r1[16], r2[16];
  if ((tid & 63) == 0) {
    r1[tid >> 6] = s1;
    r2[tid >> 6] = s2;
  }
  __syncthreads();
  if (tid == 0) {
    const double SIGMA = 0.3;
    const double H_CONST = 0.5 * log(2.0 * 3.14159265358979323846 * SIGMA * SIGMA) + 0.5;
    const float HS = (float)(H_CONST / SIGMA);
    float a1 = 0.f, a2 = 0.f;
#pragma unroll
    for (int w = 0; w < 16; ++w) {
      a1 += r1[w];
      a2 += r2[w];
    }
    out[0] = HS * a1;
    out[1] = HS * a2;
  }
}

extern "C" void kernel_launch(void* const* d_in, const int* in_sizes, int n_in,
                              void* d_out, int out_size, void* d_ws, size_t ws_size,
                              hipStream_t stream) {
  const float* ex = (const float*)d_in[0];
  const float* ey = (const float*)d_in[1];
  float* out = (float*)d_out;
  char* ws = (char*)d_ws;

  unsigned char* exn = (unsigned char*)ws;                                   // 8 MB
  unsigned char* eyn = (unsigned char*)(ws + (size_t)N_ROWS * KDIM);         // 8 MB
  int* rowmax = (int*)(ws + (size_t)N_ROWS * KDIM * 2);                      // 32 KB
  int* colmax = rowmax + N_ROWS;                                             // 32 KB

  normalize_kernel<<<2 * N_ROWS / 4, 256, 0, stream>>>(ex, ey, exn, eyn, rowmax, colmax);
  gemm_max_kernel<<<dim3(32, 32), 1024, 0, stream>>>(exn, eyn, rowmax, colmax);
  finalize_kernel<<<1, 1024, 0, stream>>>(rowmax, colmax, out);
}

// Round 17
// 195.890 us; speedup vs baseline: 1.3064x; 1.2767x over previous
//
#include <hip/hip_runtime.h>
#include <math.h>

typedef int intx4 __attribute__((ext_vector_type(4)));
typedef int intx8 __attribute__((ext_vector_type(8)));
typedef float floatx16 __attribute__((ext_vector_type(16)));

#define N_ROWS 8192
#define KDIM 1024

// E8M0 scale bytes: 123 -> 2^-4 per side (data pre-scaled by 2^4 each side)
#define SCALE_WORD 0x7B7B7B7B

// order-preserving float->int encoding for atomicMax
__device__ __forceinline__ int fenc(float f) {
  int i = __float_as_int(f);
  return i >= 0 ? i : (i ^ 0x7fffffff);
}
__device__ __forceinline__ float fdec(int e) {
  int b = e >= 0 ? e : (e ^ 0x7fffffff);
  return __int_as_float(b);
}

// async 16B global->LDS DMA (m97 pattern: per-lane global src, LDS dest must
// equal wave-uniform base + lane*16 -- ours does by construction).
__device__ __forceinline__ void gld_lds16(const void* g, void* l) {
  __builtin_amdgcn_global_load_lds(
      (const __attribute__((address_space(1))) unsigned int*)g,
      (__attribute__((address_space(3))) unsigned int*)l, 16, 0, 0);
}

// One WAVE per row (4 rows/block, no __syncthreads): computes 1/||x|| (fp32),
// writes row normalized*16 as e4m3 via HW cvt, inits the max slot.
__global__ __launch_bounds__(256) void normalize_kernel(
    const float* __restrict__ ex, const float* __restrict__ ey,
    unsigned char* __restrict__ exn, unsigned char* __restrict__ eyn,
    int* __restrict__ rowmax, int* __restrict__ colmax) {
  const int wave = threadIdx.x >> 6, lane = threadIdx.x & 63;
  const int gr = blockIdx.x * 4 + wave;  // 0..16383
  const float* x;
  unsigned char* out;
  int* mslot;
  int row;
  if (gr < N_ROWS) {
    x = ex; out = exn; mslot = rowmax; row = gr;
  } else {
    x = ey; out = eyn; mslot = colmax; row = gr - N_ROWS;
  }
  const float4* xr = (const float4*)(x + (size_t)row * KDIM);
  float4 v[4];
  float ss = 0.f;
#pragma unroll
  for (int j = 0; j < 4; ++j) {
    v[j] = xr[lane + j * 64];  // coalesced
    ss += v[j].x * v[j].x + v[j].y * v[j].y + v[j].z * v[j].z + v[j].w * v[j].w;
  }
#pragma unroll
  for (int off = 32; off > 0; off >>= 1) ss += __shfl_xor(ss, off, 64);
  const float rs = 16.0f * rsqrtf(fmaxf(ss, 1e-24f));  // 2^4 pre-scale
  int* op = (int*)(out + (size_t)row * KDIM);
#pragma unroll
  for (int j = 0; j < 4; ++j) {
    int w = __builtin_amdgcn_cvt_pk_fp8_f32(v[j].x * rs, v[j].y * rs, 0, false);
    w = __builtin_amdgcn_cvt_pk_fp8_f32(v[j].z * rs, v[j].w * rs, w, true);
    op[lane + j * 64] = w;
  }
  if (lane == 0) mslot[row] = (int)0x80000000;  // encoded -inf floor
}

// 256x256 tile GEMM (A @ B^T, row-major K-contiguous e4m3) using MX-scaled
// mfma_scale_f32_32x32x64_f8f6f4, fused with row/col max reduction.
//
// Round-28: REVERT to r22 verbatim (session best: gemm 110.2 us, total
// 194.8 us, WRITE 20.5 MB clean, VGPR 64-arch, MfmaUtil 26).
// Why: r27 falsified the fence theory -- sched_barrier(0) at every tile
// boundary left the 4-buffer spill bit-identical (262 MB WRITE, 16
// B/thread/tile). The 4-buffer family has spilled in FOUR variants
// (union-RD8 r24, shufflevector r26, fenced r27, 3-buf asm r21) while
// this 2-buffer per-tile-sync form with the SAME COMPUTE is clean. The
// allocator behavior across a widened sync interval is not controllable
// from HIP source with available tools; the spill/clean boundary sits
// exactly at this structure. Families exhausted: fine phases (r18/r19/
// r21: occupancy collapse or spill, >=144), 8-wave (r23: clean but
// TLP-starved, 137), barrier-thinning (r24/26/27: spill, >=164),
// counted vmcnt at coarse grain (r17: null). This kernel is the
// measured plateau of the explored space.
//
// Structure: 256^2 tile, 16 waves (4x4 of 64x64, acc[2][2] = 64 acc +
// ~64 arch = exactly the 128-reg cap at 4 waves/SIMD, 1 block/CU),
// 2-buffer LDS (64 KB), 1 DMA/thread/array/tile, stage t+1 before
// COMPUTE(t), one __syncthreads per K-tile (doubles as the compiler
// scheduling fence that keeps the allocator clean -- load-bearing!).
//
// LDS swizzle (verified r8): 64-B rows, 16-B chunk c of row r at slot
// c ^ ((r>>1)&3); staging pre-swizzles the per-lane global source chunk so
// the linear lane*16 dest lands swizzle-stored; fragment reads recover
// true chunk 2h+j -> operand bytes at (half,j,b) equal global
// k = k0+(2h+j)*16+b for BOTH A and B -> exact dot-product pairing.
// (Dest row = tid>>2 covers 0..255 at 1024 thr; f(row) = (tid>>3)&3;
// all read-row bases are multiples of 32 -> fsw invariant.)
__global__ __launch_bounds__(1024, 1) void gemm_max_kernel(
    const unsigned char* __restrict__ A, const unsigned char* __restrict__ B,
    int* __restrict__ rowmax, int* __restrict__ colmax) {
  constexpr int TM = 256, BK = 64, K = KDIM;
  constexpr int BUF = TM * BK;                          // 16 KB per buffer
  __shared__ __align__(16) unsigned char sA[2 * BUF];   // 32 KB
  __shared__ __align__(16) unsigned char sB[2 * BUF];   // 32 KB

  const int bm = blockIdx.x, bn = blockIdx.y;
  const int tid = threadIdx.x;  // 0..1023
  const int lane = tid & 63, wave = tid >> 6;
  const int wm = wave >> 2, wn = wave & 3;  // 4x4 waves of 64x64
  const int l32 = lane & 31, half = lane >> 5;
  const int fsw = (l32 >> 1) & 3;                 // f(row) = (row>>1)&3
  const int oLo = (((2 * half + 0) ^ fsw) << 4);  // swizzled slot offsets
  const int oHi = (((2 * half + 1) ^ fsw) << 4);

  const char* Ab = (const char*)(A + (size_t)bm * TM * K);
  const char* Bb = (const char*)(B + (size_t)bn * TM * K);

  floatx16 acc[2][2] = {};

  // Staging: 1024 lanes stage a 256x64 tile (16 KB) per array in ONE DMA.
  // Dest tid*16 -> row tid>>2 (0..255), slot tid&3.
  // Source chunk = (tid&3) ^ f(row) = (tid&3) ^ ((tid>>3)&3).
  const int src_c16 = (((tid & 3) ^ ((tid >> 3) & 3)) << 4);
  const char* gA = Ab + (size_t)(tid >> 2) * K + src_c16;
  const char* gB = Bb + (size_t)(tid >> 2) * K + src_c16;
  unsigned char* wA = sA + tid * 16;  // linear per-lane dest
  unsigned char* wB = sB + tid * 16;

#define STAGE(k0, buf)                              \
  do {                                              \
    gld_lds16(gA + (size_t)(k0), wA + (buf)*BUF);   \
    gld_lds16(gB + (size_t)(k0), wB + (buf)*BUF);   \
  } while (0)

#define COMPUTE(cur)                                                        \
  do {                                                                      \
    intx8 aF[2];                                                            \
    _Pragma("unroll") for (int mi = 0; mi < 2; ++mi) {                      \
      const unsigned char* aBase =                                          \
          &sA[(cur)*BUF + (wm * 64 + mi * 32 + l32) * BK];                  \
      const intx4 lo = *(const intx4*)(aBase + oLo);                        \
      const intx4 hi = *(const intx4*)(aBase + oHi);                        \
      aF[mi] = __builtin_shufflevector(lo, hi, 0, 1, 2, 3, 4, 5, 6, 7);     \
    }                                                                       \
    _Pragma("unroll") for (int ni = 0; ni < 2; ++ni) {                      \
      const unsigned char* bBase =                                          \
          &sB[(cur)*BUF + (wn * 64 + ni * 32 + l32) * BK];                  \
      const intx4 lo = *(const intx4*)(bBase + oLo);                        \
      const intx4 hi = *(const intx4*)(bBase + oHi);                        \
      const intx8 bF =                                                      \
          __builtin_shufflevector(lo, hi, 0, 1, 2, 3, 4, 5, 6, 7);          \
      _Pragma("unroll") for (int mi = 0; mi < 2; ++mi)                      \
          acc[mi][ni] = __builtin_amdgcn_mfma_scale_f32_32x32x64_f8f6f4(    \
              aF[mi], bF, acc[mi][ni], 0, 0, 0, SCALE_WORD, 0,              \
              SCALE_WORD);                                                  \
    }                                                                       \
  } while (0)

  // Prologue: DMA buf0; barrier drains vmcnt(0) -> tile 0 resident.
  STAGE(0, 0);
  __syncthreads();

  // Steady state (r15 schedule): DMA for s+1 (other buffer) issues BEFORE
  // COMPUTE(s); its latency hides under the MFMA phase; the single
  // end-of-step barrier (vmcnt drain) makes it resident for next step.
#pragma unroll 1
  for (int step = 0; step < K / BK - 1; ++step) {
    STAGE((size_t)(step + 1) * BK, (step + 1) & 1);
    COMPUTE(step & 1);
    __syncthreads();
  }
  COMPUTE((K / BK - 1) & 1);

#undef STAGE
#undef COMPUTE

  // 32x32 C/D layout (m74/m101, dtype-independent):
  //   col = lane&31, row = (reg&3) + 8*(reg>>2) + 4*(lane>>5), reg in [0,16)
  // Row maxes: in-lane over ni, shuffle across 32 cols (masks 1..16 stay
  // within a half), l32==0 lanes write.
#pragma unroll
  for (int mi = 0; mi < 2; ++mi) {
#pragma unroll
    for (int reg = 0; reg < 16; ++reg) {
      float v = fmaxf(acc[mi][0][reg], acc[mi][1][reg]);
#pragma unroll
      for (int m = 1; m < 32; m <<= 1) v = fmaxf(v, __shfl_xor(v, m, 64));
      if (l32 == 0) {
        const int grow = bm * TM + wm * 64 + mi * 32 +
                         (reg & 3) + 8 * (reg >> 2) + 4 * half;
        atomicMax(&rowmax[grow], fenc(v));
      }
    }
  }
  // Col maxes: in-lane over mi,reg (32 vals), combine halves via xor 32.
#pragma unroll
  for (int ni = 0; ni < 2; ++ni) {
    float v = -3.402823466e38f;
#pragma unroll
    for (int mi = 0; mi < 2; ++mi)
#pragma unroll
      for (int reg = 0; reg < 16; ++reg) v = fmaxf(v, acc[mi][ni][reg]);
    v = fmaxf(v, __shfl_xor(v, 32, 64));
    if (half == 0) {
      const int gcol = bn * TM + wn * 64 + ni * 32 + l32;
      atomicMax(&colmax[gcol], fenc(v));
    }
  }
}

__global__ __launch_bounds__(1024) void finalize_kernel(
    const int* __restrict__ rowmax, const int* __restrict__ colmax,
    float* __restrict__ out) {
  const int tid = threadIdx.x;
  float s1 = 0.f, s2 = 0.f;
  for (int i = tid; i < N_ROWS; i += 1024) {
    s1 += 1.0f - fdec(rowmax[i]);
    s2 += 1.0f - fdec(colmax[i]);
  }
#pragma unroll
  for (int off = 32; off > 0; off >>= 1) {
    s1 += __shfl_down(s1, off, 64);
    s2 += __shfl_down(s2, off, 64);
  }
  __shared__ float r1[16], r2[16];
  if ((tid & 63) == 0) {
    r1[tid >> 6] = s1;
    r2[tid >> 6] = s2;
  }
  __syncthreads();
  if (tid == 0) {
    const double SIGMA = 0.3;
    const double H_CONST = 0.5 * log(2.0 * 3.14159265358979323846 * SIGMA * SIGMA) + 0.5;
    const float HS = (float)(H_CONST / SIGMA);
    float a1 = 0.f, a2 = 0.f;
#pragma unroll
    for (int w = 0; w < 16; ++w) {
      a1 += r1[w];
      a2 += r2[w];
    }
    out[0] = HS * a1;
    out[1] = HS * a2;
  }
}

extern "C" void kernel_launch(void* const* d_in, const int* in_sizes, int n_in,
                              void* d_out, int out_size, void* d_ws, size_t ws_size,
                              hipStream_t stream) {
  const float* ex = (const float*)d_in[0];
  const float* ey = (const float*)d_in[1];
  float* out = (float*)d_out;
  char* ws = (char*)d_ws;

  unsigned char* exn = (unsigned char*)ws;                                   // 8 MB
  unsigned char* eyn = (unsigned char*)(ws + (size_t)N_ROWS * KDIM);         // 8 MB
  int* rowmax = (int*)(ws + (size_t)N_ROWS * KDIM * 2);                      // 32 KB
  int* colmax = rowmax + N_ROWS;                                             // 32 KB

  normalize_kernel<<<2 * N_ROWS / 4, 256, 0, stream>>>(ex, ey, exn, eyn, rowmax, colmax);
  gemm_max_kernel<<<dim3(32, 32), 1024, 0, stream>>>(exn, eyn, rowmax, colmax);
  finalize_kernel<<<1, 1024, 0, stream>>>(rowmax, colmax, out);
}